// Round 1
// baseline (697.496 us; speedup 1.0000x reference)
//
#include <hip/hip_runtime.h>

// MultiHeadAttention fused block, MI355X gfx950.
// B=256, NA=128, E=1024, H=16, HD=64. M = B*NA = 32768 rows.
//
// Pipeline:
//   K0: in_w fp32 -> bf16                   (Wb)
//   K1: LN1(x) -> bf16                      (xnb)
//   K2: MFMA GEMM xnb @ Wb^T + bias -> Qb(.125 folded), Kb, Vb (bf16)
//   K3: per-group attention (4096 groups of 128x64), MFMA QK^T + softmax + PV
//       -> attnb (bf16, overlays xnb), avg_w -> d_out tail
//   K4: recompute LN1 stats, residual + LN2 -> d_out
//
// Workspace layout (bytes):
//   [0,            67108864)  xnb / attnb (bf16, 33554432 elems)  -- reused
//   [67108864,    134217728)  Qb
//   [134217728,   201326592)  Kb
//   [201326592,   268435456)  Vb
//   [268435456,   274726912)  Wb (3072*1024 bf16)
// Total 274.7 MB.

typedef __attribute__((ext_vector_type(4))) float float4v;
typedef __attribute__((ext_vector_type(4))) int   int4v;
typedef __attribute__((ext_vector_type(8))) short short8v;
typedef __attribute__((ext_vector_type(4))) short short4v;

#define LN_EPS 1e-5f

__device__ __forceinline__ unsigned short f2bf(float f) {
    unsigned int u = __float_as_uint(f);
    u += 0x7FFFu + ((u >> 16) & 1u);   // round-to-nearest-even
    return (unsigned short)(u >> 16);
}
__device__ __forceinline__ float bf2f(unsigned short h) {
    return __uint_as_float(((unsigned int)h) << 16);
}

// ---------------------------------------------------------------- K0: W->bf16
__global__ __launch_bounds__(256) void k0_w_to_bf16(const float* __restrict__ w,
                                                    unsigned short* __restrict__ wb) {
    int idx = blockIdx.x * 256 + threadIdx.x;      // one thread per 8 elems
    const float4v* src = (const float4v*)w;
    float4v a = src[idx * 2];
    float4v b = src[idx * 2 + 1];
    short8v o;
    o[0] = (short)f2bf(a[0]); o[1] = (short)f2bf(a[1]);
    o[2] = (short)f2bf(a[2]); o[3] = (short)f2bf(a[3]);
    o[4] = (short)f2bf(b[0]); o[5] = (short)f2bf(b[1]);
    o[6] = (short)f2bf(b[2]); o[7] = (short)f2bf(b[3]);
    *((short8v*)wb + idx) = o;
}

// --------------------------------------------------------- block reduction
__device__ __forceinline__ void block_reduce_2(float& s, float& s2, float* red) {
    #pragma unroll
    for (int off = 32; off > 0; off >>= 1) {
        s  += __shfl_xor(s, off, 64);
        s2 += __shfl_xor(s2, off, 64);
    }
    __syncthreads();                      // also protects re-use of red
    if ((threadIdx.x & 63) == 0) {
        red[(threadIdx.x >> 6) * 2]     = s;
        red[(threadIdx.x >> 6) * 2 + 1] = s2;
    }
    __syncthreads();
    s  = red[0] + red[2] + red[4] + red[6];
    s2 = red[1] + red[3] + red[5] + red[7];
}

// ---------------------------------------------------------------- K1: LN1
__global__ __launch_bounds__(256) void k1_ln1(const float* __restrict__ x,
                                              const float* __restrict__ w1,
                                              const float* __restrict__ b1,
                                              unsigned short* __restrict__ xnb) {
    __shared__ float red[8];
    int row = blockIdx.x;
    int tid = threadIdx.x;
    float4v xv = ((const float4v*)(x + (size_t)row * 1024))[tid];
    float s  = xv[0] + xv[1] + xv[2] + xv[3];
    float s2 = xv[0]*xv[0] + xv[1]*xv[1] + xv[2]*xv[2] + xv[3]*xv[3];
    block_reduce_2(s, s2, red);
    float mean = s * (1.0f / 1024.0f);
    float var  = s2 * (1.0f / 1024.0f) - mean * mean;
    float rs   = rsqrtf(var + LN_EPS);
    float4v wv = ((const float4v*)w1)[tid];
    float4v bv = ((const float4v*)b1)[tid];
    short4v o;
    #pragma unroll
    for (int c = 0; c < 4; ++c)
        o[c] = (short)f2bf((xv[c] - mean) * rs * wv[c] + bv[c]);
    ((short4v*)(xnb + (size_t)row * 1024))[tid] = o;
}

// ---------------------------------------------------------------- K2: QKV GEMM
// C[m][n] = sum_k A[m][k] * W[n][k] + bias[n];  A: 32768x1024, W: 3072x1024.
// 128x128 tile, BK=32, 4 waves (2x2), each wave 4x4 MFMA tiles of 16x16x32.
__global__ __launch_bounds__(256) void k2_qkv_gemm(const unsigned short* __restrict__ A,
                                                   const unsigned short* __restrict__ W,
                                                   const float* __restrict__ bias,
                                                   unsigned short* __restrict__ Qb,
                                                   unsigned short* __restrict__ Kb,
                                                   unsigned short* __restrict__ Vb) {
    __shared__ unsigned short sA[128 * 32];
    __shared__ unsigned short sB[128 * 32];
    int bx = blockIdx.x;
    int nT = bx % 24;          // N-fastest for W L2 locality
    int mT = bx / 24;
    int rowBase = mT * 128;
    int colBase = nT * 128;
    int tid  = threadIdx.x;
    int lane = tid & 63;
    int wave = tid >> 6;
    int wm = wave >> 1, wn = wave & 1;
    int l15 = lane & 15, q4 = lane >> 4;
    int ldRow = tid >> 2;         // 0..63
    int ldK   = (tid & 3) * 8;    // 0,8,16,24
    const unsigned short* aPtr = A + (size_t)(rowBase + ldRow) * 1024 + ldK;
    const unsigned short* wPtr = W + (size_t)(colBase + ldRow) * 1024 + ldK;

    float4v zero4 = {0.f, 0.f, 0.f, 0.f};
    float4v acc[4][4];
    #pragma unroll
    for (int i = 0; i < 4; ++i)
        #pragma unroll
        for (int jj = 0; jj < 4; ++jj) acc[i][jj] = zero4;

    for (int k0 = 0; k0 < 1024; k0 += 32) {
        int4v a0 = *(const int4v*)(aPtr + k0);
        int4v a1 = *(const int4v*)(aPtr + 64 * 1024 + k0);
        int4v b0 = *(const int4v*)(wPtr + k0);
        int4v b1 = *(const int4v*)(wPtr + 64 * 1024 + k0);
        __syncthreads();
        *(int4v*)(sA + ldRow * 32 + ldK)        = a0;
        *(int4v*)(sA + (64 + ldRow) * 32 + ldK) = a1;
        *(int4v*)(sB + ldRow * 32 + ldK)        = b0;
        *(int4v*)(sB + (64 + ldRow) * 32 + ldK) = b1;
        __syncthreads();
        short8v af[4], bfr[4];
        #pragma unroll
        for (int t = 0; t < 4; ++t) {
            af[t]  = *(const short8v*)(sA + (wm * 64 + t * 16 + l15) * 32 + q4 * 8);
            bfr[t] = *(const short8v*)(sB + (wn * 64 + t * 16 + l15) * 32 + q4 * 8);
        }
        #pragma unroll
        for (int tm = 0; tm < 4; ++tm)
            #pragma unroll
            for (int tn = 0; tn < 4; ++tn)
                acc[tm][tn] = __builtin_amdgcn_mfma_f32_16x16x32_bf16(af[tm], bfr[tn], acc[tm][tn], 0, 0, 0);
    }

    // Epilogue: route 128-col tile to Q (scaled 1/8), K, or V (tiles never straddle).
    int which = colBase >> 10;
    unsigned short* outb = (which == 0) ? Qb : (which == 1) ? Kb : Vb;
    float scale = (which == 0) ? 0.125f : 1.0f;
    #pragma unroll
    for (int tn = 0; tn < 4; ++tn) {
        int gcol = colBase + wn * 64 + tn * 16 + l15;
        float bval = bias[gcol];
        int lcol = gcol & 1023;
        #pragma unroll
        for (int tm = 0; tm < 4; ++tm) {
            #pragma unroll
            for (int g = 0; g < 4; ++g) {
                int grow = rowBase + wm * 64 + tm * 16 + q4 * 4 + g;
                outb[(size_t)grow * 1024 + lcol] = f2bf((acc[tm][tn][g] + bval) * scale);
            }
        }
    }
}

// ---------------------------------------------------------------- K3: attention
// One block per group j (4096). Element [j][i][d] lives at flat i*262144 + j*64 + d.
#define QK_S 72
#define P_S  136
#define VT_S 136
__global__ __launch_bounds__(256) void k3_attn(const unsigned short* __restrict__ Qb,
                                               const unsigned short* __restrict__ Kb,
                                               const unsigned short* __restrict__ Vb,
                                               unsigned short* __restrict__ attnb,
                                               float* __restrict__ avgw) {
    __shared__ unsigned short region0[128 * QK_S * 2];  // sQ | sK, later sP (128*136 fits)
    __shared__ unsigned short sVt[64 * VT_S];
    __shared__ float wred[2][2][128];                   // [max/sum][wn][row]
    __shared__ float colsum[128];
    unsigned short* sQ = region0;
    unsigned short* sK = region0 + 128 * QK_S;
    unsigned short* sP = region0;

    int j = blockIdx.x;
    int tid = threadIdx.x;
    int lane = tid & 63;
    int wave = tid >> 6;
    int wm = wave >> 1, wn = wave & 1;
    int q4 = lane >> 4, l15 = lane & 15;
    size_t base = (size_t)j * 64;

    if (tid < 128) colsum[tid] = 0.f;
    for (int idx = tid; idx < 1024; idx += 256) {       // Q,K: 128 rows x 64, 8-elem chunks
        int i = idx >> 3, seg = (idx & 7) * 8;
        *(int4v*)(sQ + i * QK_S + seg) = *(const int4v*)(Qb + base + (size_t)i * 262144 + seg);
        *(int4v*)(sK + i * QK_S + seg) = *(const int4v*)(Kb + base + (size_t)i * 262144 + seg);
    }
    for (int idx = tid; idx < 8192; idx += 256) {       // V transposed: sVt[d][m]
        int m = idx >> 6, d = idx & 63;
        sVt[d * VT_S + m] = Vb[base + (size_t)m * 262144 + d];
    }
    __syncthreads();

    // Phase A: S = Q K^T  (wave (wm,wn) covers rows wm*64.., cols wn*64..)
    float4v zero4 = {0.f, 0.f, 0.f, 0.f};
    float4v S[4][4];
    #pragma unroll
    for (int a = 0; a < 4; ++a)
        #pragma unroll
        for (int b = 0; b < 4; ++b) S[a][b] = zero4;
    #pragma unroll
    for (int ks = 0; ks < 2; ++ks) {
        short8v qf[4], kf[4];
        #pragma unroll
        for (int t = 0; t < 4; ++t) {
            qf[t] = *(const short8v*)(sQ + (wm * 64 + t * 16 + l15) * QK_S + q4 * 8 + ks * 32);
            kf[t] = *(const short8v*)(sK + (wn * 64 + t * 16 + l15) * QK_S + q4 * 8 + ks * 32);
        }
        #pragma unroll
        for (int tm = 0; tm < 4; ++tm)
            #pragma unroll
            for (int tn = 0; tn < 4; ++tn)
                S[tm][tn] = __builtin_amdgcn_mfma_f32_16x16x32_bf16(qf[tm], kf[tn], S[tm][tn], 0, 0, 0);
    }

    // Row max (wave-local 64 cols -> cross-wave via LDS)
    float rmax[4][4];
    #pragma unroll
    for (int tm = 0; tm < 4; ++tm)
        #pragma unroll
        for (int g = 0; g < 4; ++g)
            rmax[tm][g] = fmaxf(fmaxf(S[tm][0][g], S[tm][1][g]), fmaxf(S[tm][2][g], S[tm][3][g]));
    #pragma unroll
    for (int off = 1; off <= 8; off <<= 1)
        #pragma unroll
        for (int tm = 0; tm < 4; ++tm)
            #pragma unroll
            for (int g = 0; g < 4; ++g)
                rmax[tm][g] = fmaxf(rmax[tm][g], __shfl_xor(rmax[tm][g], off, 64));
    if (l15 == 0) {
        #pragma unroll
        for (int tm = 0; tm < 4; ++tm)
            #pragma unroll
            for (int g = 0; g < 4; ++g)
                wred[0][wn][wm * 64 + tm * 16 + q4 * 4 + g] = rmax[tm][g];
    }
    __syncthreads();

    // exp + row sum
    float rsum[4][4];
    #pragma unroll
    for (int tm = 0; tm < 4; ++tm)
        #pragma unroll
        for (int g = 0; g < 4; ++g) {
            int r = wm * 64 + tm * 16 + q4 * 4 + g;
            float rm = fmaxf(wred[0][0][r], wred[0][1][r]);
            float t0 = 0.f;
            #pragma unroll
            for (int tn = 0; tn < 4; ++tn) {
                float e = __expf(S[tm][tn][g] - rm);
                S[tm][tn][g] = e;
                t0 += e;
            }
            rsum[tm][g] = t0;
        }
    #pragma unroll
    for (int off = 1; off <= 8; off <<= 1)
        #pragma unroll
        for (int tm = 0; tm < 4; ++tm)
            #pragma unroll
            for (int g = 0; g < 4; ++g)
                rsum[tm][g] += __shfl_xor(rsum[tm][g], off, 64);
    if (l15 == 0) {
        #pragma unroll
        for (int tm = 0; tm < 4; ++tm)
            #pragma unroll
            for (int g = 0; g < 4; ++g)
                wred[1][wn][wm * 64 + tm * 16 + q4 * 4 + g] = rsum[tm][g];
    }
    __syncthreads();

    // normalize w = e / rowsum
    #pragma unroll
    for (int tm = 0; tm < 4; ++tm)
        #pragma unroll
        for (int g = 0; g < 4; ++g) {
            int r = wm * 64 + tm * 16 + q4 * 4 + g;
            float inv = 1.0f / (wred[1][0][r] + wred[1][1][r]);
            #pragma unroll
            for (int tn = 0; tn < 4; ++tn) S[tm][tn][g] *= inv;
        }

    // avg_w column sums (sum over query rows)
    float cs[4];
    #pragma unroll
    for (int tn = 0; tn < 4; ++tn) {
        float t0 = 0.f;
        #pragma unroll
        for (int tm = 0; tm < 4; ++tm)
            #pragma unroll
            for (int g = 0; g < 4; ++g) t0 += S[tm][tn][g];
        cs[tn] = t0;
    }
    #pragma unroll
    for (int off = 16; off <= 32; off <<= 1)
        #pragma unroll
        for (int tn = 0; tn < 4; ++tn) cs[tn] += __shfl_xor(cs[tn], off, 64);
    if (lane < 16) {
        #pragma unroll
        for (int tn = 0; tn < 4; ++tn)
            atomicAdd(&colsum[wn * 64 + tn * 16 + lane], cs[tn]);
    }
    __syncthreads();   // sQ/sK reads & colsum atomics complete block-wide

    // write P (bf16) into region0 (aliases sQ/sK — safe now)
    #pragma unroll
    for (int tm = 0; tm < 4; ++tm)
        #pragma unroll
        for (int tn = 0; tn < 4; ++tn)
            #pragma unroll
            for (int g = 0; g < 4; ++g)
                sP[(wm * 64 + tm * 16 + q4 * 4 + g) * P_S + wn * 64 + tn * 16 + l15] = f2bf(S[tm][tn][g]);
    __syncthreads();

    if (tid < 128) avgw[(size_t)j * 128 + tid] = colsum[tid] * (1.0f / 16.0f);

    // Phase C: O = P V (via transposed V). Wave covers rows wm*64.., cols wn*32..
    float4v O[4][2];
    #pragma unroll
    for (int a = 0; a < 4; ++a) { O[a][0] = zero4; O[a][1] = zero4; }
    #pragma unroll
    for (int ks = 0; ks < 4; ++ks) {
        short8v pf[4], vf[2];
        #pragma unroll
        for (int t = 0; t < 4; ++t)
            pf[t] = *(const short8v*)(sP + (wm * 64 + t * 16 + l15) * P_S + q4 * 8 + ks * 32);
        #pragma unroll
        for (int t = 0; t < 2; ++t)
            vf[t] = *(const short8v*)(sVt + (wn * 32 + t * 16 + l15) * VT_S + q4 * 8 + ks * 32);
        #pragma unroll
        for (int tm = 0; tm < 4; ++tm)
            #pragma unroll
            for (int tn = 0; tn < 2; ++tn)
                O[tm][tn] = __builtin_amdgcn_mfma_f32_16x16x32_bf16(pf[tm], vf[tn], O[tm][tn], 0, 0, 0);
    }
    #pragma unroll
    for (int tm = 0; tm < 4; ++tm)
        #pragma unroll
        for (int tn = 0; tn < 2; ++tn)
            #pragma unroll
            for (int g = 0; g < 4; ++g) {
                int i = wm * 64 + tm * 16 + q4 * 4 + g;
                int d = wn * 32 + tn * 16 + l15;
                attnb[base + (size_t)i * 262144 + d] = f2bf(O[tm][tn][g]);
            }
}

// ---------------------------------------------------------------- K4: residual + LN2
__global__ __launch_bounds__(256) void k4_ln2(const float* __restrict__ x,
                                              const float* __restrict__ w1,
                                              const float* __restrict__ b1,
                                              const unsigned short* __restrict__ attnb,
                                              const float* __restrict__ w2,
                                              const float* __restrict__ b2,
                                              float* __restrict__ out) {
    __shared__ float red[8];
    int row = blockIdx.x;
    int tid = threadIdx.x;
    float4v xv = ((const float4v*)(x + (size_t)row * 1024))[tid];
    float s  = xv[0] + xv[1] + xv[2] + xv[3];
    float s2 = xv[0]*xv[0] + xv[1]*xv[1] + xv[2]*xv[2] + xv[3]*xv[3];
    block_reduce_2(s, s2, red);
    float mean = s * (1.0f / 1024.0f);
    float var  = s2 * (1.0f / 1024.0f) - mean * mean;
    float rs   = rsqrtf(var + LN_EPS);
    float4v wv = ((const float4v*)w1)[tid];
    float4v bv = ((const float4v*)b1)[tid];
    short4v av = ((const short4v*)(attnb + (size_t)row * 1024))[tid];
    float4v r;
    #pragma unroll
    for (int c = 0; c < 4; ++c)
        r[c] = (xv[c] - mean) * rs * wv[c] + bv[c] + bf2f((unsigned short)av[c]);
    s  = r[0] + r[1] + r[2] + r[3];
    s2 = r[0]*r[0] + r[1]*r[1] + r[2]*r[2] + r[3]*r[3];
    block_reduce_2(s, s2, red);
    float mean2 = s * (1.0f / 1024.0f);
    float var2  = s2 * (1.0f / 1024.0f) - mean2 * mean2;
    float rs2   = rsqrtf(var2 + LN_EPS);
    float4v w2v = ((const float4v*)w2)[tid];
    float4v b2v = ((const float4v*)b2)[tid];
    float4v o;
    #pragma unroll
    for (int c = 0; c < 4; ++c)
        o[c] = (r[c] - mean2) * rs2 * w2v[c] + b2v[c];
    ((float4v*)(out + (size_t)row * 1024))[tid] = o;
}

// ---------------------------------------------------------------- launch
extern "C" void kernel_launch(void* const* d_in, const int* in_sizes, int n_in,
                              void* d_out, int out_size, void* d_ws, size_t ws_size,
                              hipStream_t stream) {
    const float* x    = (const float*)d_in[0];
    const float* ln1w = (const float*)d_in[1];
    const float* ln1b = (const float*)d_in[2];
    const float* inw  = (const float*)d_in[3];
    const float* inb  = (const float*)d_in[4];
    const float* ln2w = (const float*)d_in[5];
    const float* ln2b = (const float*)d_in[6];
    float* out  = (float*)d_out;
    float* avgw = out + 33554432;           // 256*128*1024

    char* ws = (char*)d_ws;                 // needs ~275 MB
    unsigned short* xnb = (unsigned short*)(ws);                 // also attnb (reused)
    unsigned short* Qb  = (unsigned short*)(ws + 67108864);
    unsigned short* Kb  = (unsigned short*)(ws + 134217728);
    unsigned short* Vb  = (unsigned short*)(ws + 201326592);
    unsigned short* Wb  = (unsigned short*)(ws + 268435456);

    k0_w_to_bf16<<<1536, 256, 0, stream>>>(inw, Wb);
    k1_ln1<<<32768, 256, 0, stream>>>(x, ln1w, ln1b, xnb);
    k2_qkv_gemm<<<6144, 256, 0, stream>>>(xnb, Wb, inb, Qb, Kb, Vb);
    k3_attn<<<4096, 256, 0, stream>>>(Qb, Kb, Vb, xnb /*attnb*/, avgw);
    k4_ln2<<<32768, 256, 0, stream>>>(x, ln1w, ln1b, xnb /*attnb*/, ln2w, ln2b, out);
}

// Round 2
// 669.647 us; speedup vs baseline: 1.0416x; 1.0416x over previous
//
#include <hip/hip_runtime.h>

// MultiHeadAttention fused block, MI355X gfx950.
// B=256, NA=128, E=1024, H=16, HD=64. M = B*NA = 32768 rows.
//
// Pipeline:
//   K0: in_w fp32 -> bf16                   (Wb)
//   K1: LN1(x) -> bf16                      (xnb)
//   K2: MFMA GEMM xnb @ Wb^T + bias -> Qb(.125 folded), Kb, Vb (bf16)
//       R2: staging via __builtin_amdgcn_global_load_lds width=16 (m97 structure)
//   K3: per-group attention (4096 groups of 128x64), MFMA QK^T + softmax + PV
//       -> attnb (bf16, overlays xnb), avg_w -> d_out tail
//       R2: V staged with 16B vectorized global reads + LDS transpose
//   K4: recompute LN1 stats, residual + LN2 -> d_out
//
// Workspace layout (bytes):
//   [0,            67108864)  xnb / attnb (bf16, 33554432 elems)  -- reused
//   [67108864,    134217728)  Qb
//   [134217728,   201326592)  Kb
//   [201326592,   268435456)  Vb
//   [268435456,   274726912)  Wb (3072*1024 bf16)
// Total 274.7 MB.

typedef __attribute__((ext_vector_type(4))) float float4v;
typedef __attribute__((ext_vector_type(4))) int   int4v;
typedef __attribute__((ext_vector_type(8))) short short8v;
typedef __attribute__((ext_vector_type(4))) short short4v;

#define LN_EPS 1e-5f

// Direct global->LDS DMA, 16 B per lane. LDS base must be wave-uniform;
// hardware writes base + lane*16.
#define GLL(g, l) __builtin_amdgcn_global_load_lds( \
    (const __attribute__((address_space(1))) unsigned int*)(g), \
    (__attribute__((address_space(3))) unsigned int*)(l), 16, 0, 0)

__device__ __forceinline__ unsigned short f2bf(float f) {
    unsigned int u = __float_as_uint(f);
    u += 0x7FFFu + ((u >> 16) & 1u);   // round-to-nearest-even
    return (unsigned short)(u >> 16);
}
__device__ __forceinline__ float bf2f(unsigned short h) {
    return __uint_as_float(((unsigned int)h) << 16);
}

// ---------------------------------------------------------------- K0: W->bf16
__global__ __launch_bounds__(256) void k0_w_to_bf16(const float* __restrict__ w,
                                                    unsigned short* __restrict__ wb) {
    int idx = blockIdx.x * 256 + threadIdx.x;      // one thread per 8 elems
    const float4v* src = (const float4v*)w;
    float4v a = src[idx * 2];
    float4v b = src[idx * 2 + 1];
    short8v o;
    o[0] = (short)f2bf(a[0]); o[1] = (short)f2bf(a[1]);
    o[2] = (short)f2bf(a[2]); o[3] = (short)f2bf(a[3]);
    o[4] = (short)f2bf(b[0]); o[5] = (short)f2bf(b[1]);
    o[6] = (short)f2bf(b[2]); o[7] = (short)f2bf(b[3]);
    *((short8v*)wb + idx) = o;
}

// --------------------------------------------------------- block reduction
__device__ __forceinline__ void block_reduce_2(float& s, float& s2, float* red) {
    #pragma unroll
    for (int off = 32; off > 0; off >>= 1) {
        s  += __shfl_xor(s, off, 64);
        s2 += __shfl_xor(s2, off, 64);
    }
    __syncthreads();                      // also protects re-use of red
    if ((threadIdx.x & 63) == 0) {
        red[(threadIdx.x >> 6) * 2]     = s;
        red[(threadIdx.x >> 6) * 2 + 1] = s2;
    }
    __syncthreads();
    s  = red[0] + red[2] + red[4] + red[6];
    s2 = red[1] + red[3] + red[5] + red[7];
}

// ---------------------------------------------------------------- K1: LN1
__global__ __launch_bounds__(256) void k1_ln1(const float* __restrict__ x,
                                              const float* __restrict__ w1,
                                              const float* __restrict__ b1,
                                              unsigned short* __restrict__ xnb) {
    __shared__ float red[8];
    int row = blockIdx.x;
    int tid = threadIdx.x;
    float4v xv = ((const float4v*)(x + (size_t)row * 1024))[tid];
    float s  = xv[0] + xv[1] + xv[2] + xv[3];
    float s2 = xv[0]*xv[0] + xv[1]*xv[1] + xv[2]*xv[2] + xv[3]*xv[3];
    block_reduce_2(s, s2, red);
    float mean = s * (1.0f / 1024.0f);
    float var  = s2 * (1.0f / 1024.0f) - mean * mean;
    float rs   = rsqrtf(var + LN_EPS);
    float4v wv = ((const float4v*)w1)[tid];
    float4v bv = ((const float4v*)b1)[tid];
    short4v o;
    #pragma unroll
    for (int c = 0; c < 4; ++c)
        o[c] = (short)f2bf((xv[c] - mean) * rs * wv[c] + bv[c]);
    ((short4v*)(xnb + (size_t)row * 1024))[tid] = o;
}

// ---------------------------------------------------------------- K2: QKV GEMM
// C[m][n] = sum_k A[m][k] * W[n][k] + bias[n];  A: 32768x1024, W: 3072x1024.
// 128x128 tile, BK=32, 4 waves (2x2), each wave 4x4 MFMA tiles of 16x16x32.
// Staging: global_load_lds dwordx4 — wave w stages rows [w*16, w*16+16) of
// each 64-row half; LDS layout [128][32] shorts row-major (lane-order match).
__global__ __launch_bounds__(256) void k2_qkv_gemm(const unsigned short* __restrict__ A,
                                                   const unsigned short* __restrict__ W,
                                                   const float* __restrict__ bias,
                                                   unsigned short* __restrict__ Qb,
                                                   unsigned short* __restrict__ Kb,
                                                   unsigned short* __restrict__ Vb) {
    __shared__ unsigned short sA[128 * 32];
    __shared__ unsigned short sB[128 * 32];
    int bx = blockIdx.x;
    int nT = bx % 24;          // N-fastest for W L2 locality
    int mT = bx / 24;
    int rowBase = mT * 128;
    int colBase = nT * 128;
    int tid  = threadIdx.x;
    int lane = tid & 63;
    int wave = tid >> 6;
    int wm = wave >> 1, wn = wave & 1;
    int l15 = lane & 15, q4 = lane >> 4;

    // staging addresses: wave w covers rows w*16..w*16+15 of each half
    int sRow = wave * 16 + (lane >> 2);   // row within 64-row half
    int sKo  = (lane & 3) * 8;            // k-offset in shorts
    const unsigned short* aG0 = A + (size_t)(rowBase + sRow) * 1024 + sKo;
    const unsigned short* aG1 = aG0 + (size_t)64 * 1024;
    const unsigned short* wG0 = W + (size_t)(colBase + sRow) * 1024 + sKo;
    const unsigned short* wG1 = wG0 + (size_t)64 * 1024;
    unsigned short* sA0 = sA + wave * 16 * 32;          // wave-uniform LDS bases
    unsigned short* sA1 = sA + (64 + wave * 16) * 32;
    unsigned short* sB0 = sB + wave * 16 * 32;
    unsigned short* sB1 = sB + (64 + wave * 16) * 32;

    float4v zero4 = {0.f, 0.f, 0.f, 0.f};
    float4v acc[4][4];
    #pragma unroll
    for (int i = 0; i < 4; ++i)
        #pragma unroll
        for (int jj = 0; jj < 4; ++jj) acc[i][jj] = zero4;

    for (int k0 = 0; k0 < 1024; k0 += 32) {
        __syncthreads();                   // previous tile's ds_reads complete
        GLL(aG0 + k0, sA0);
        GLL(aG1 + k0, sA1);
        GLL(wG0 + k0, sB0);
        GLL(wG1 + k0, sB1);
        __syncthreads();                   // drains vmcnt(0) before ds_read
        short8v af[4], bfr[4];
        #pragma unroll
        for (int t = 0; t < 4; ++t) {
            af[t]  = *(const short8v*)(sA + (wm * 64 + t * 16 + l15) * 32 + q4 * 8);
            bfr[t] = *(const short8v*)(sB + (wn * 64 + t * 16 + l15) * 32 + q4 * 8);
        }
        #pragma unroll
        for (int tm = 0; tm < 4; ++tm)
            #pragma unroll
            for (int tn = 0; tn < 4; ++tn)
                acc[tm][tn] = __builtin_amdgcn_mfma_f32_16x16x32_bf16(af[tm], bfr[tn], acc[tm][tn], 0, 0, 0);
    }

    // Epilogue: route 128-col tile to Q (scaled 1/8), K, or V (tiles never straddle).
    int which = colBase >> 10;
    unsigned short* outb = (which == 0) ? Qb : (which == 1) ? Kb : Vb;
    float scale = (which == 0) ? 0.125f : 1.0f;
    #pragma unroll
    for (int tn = 0; tn < 4; ++tn) {
        int gcol = colBase + wn * 64 + tn * 16 + l15;
        float bval = bias[gcol];
        int lcol = gcol & 1023;
        #pragma unroll
        for (int tm = 0; tm < 4; ++tm) {
            #pragma unroll
            for (int g = 0; g < 4; ++g) {
                int grow = rowBase + wm * 64 + tm * 16 + q4 * 4 + g;
                outb[(size_t)grow * 1024 + lcol] = f2bf((acc[tm][tn][g] + bval) * scale);
            }
        }
    }
}

// ---------------------------------------------------------------- K3: attention
// One block per group j (4096). Element [j][i][d] lives at flat i*262144 + j*64 + d.
#define QK_S 72
#define P_S  136
#define VT_S 136
__global__ __launch_bounds__(256) void k3_attn(const unsigned short* __restrict__ Qb,
                                               const unsigned short* __restrict__ Kb,
                                               const unsigned short* __restrict__ Vb,
                                               unsigned short* __restrict__ attnb,
                                               float* __restrict__ avgw) {
    __shared__ unsigned short region0[128 * QK_S * 2];  // sQ | sK, later sP (128*136 fits)
    __shared__ unsigned short sVt[64 * VT_S];
    __shared__ float wred[2][2][128];                   // [max/sum][wn][row]
    __shared__ float colsum[128];
    unsigned short* sQ = region0;
    unsigned short* sK = region0 + 128 * QK_S;
    unsigned short* sP = region0;

    int j = blockIdx.x;
    int tid = threadIdx.x;
    int lane = tid & 63;
    int wave = tid >> 6;
    int wm = wave >> 1, wn = wave & 1;
    int q4 = lane >> 4, l15 = lane & 15;
    size_t base = (size_t)j * 64;

    if (tid < 128) colsum[tid] = 0.f;
    for (int idx = tid; idx < 1024; idx += 256) {       // Q,K: 128 rows x 64, 8-elem chunks
        int i = idx >> 3, seg = (idx & 7) * 8;
        *(int4v*)(sQ + i * QK_S + seg) = *(const int4v*)(Qb + base + (size_t)i * 262144 + seg);
        *(int4v*)(sK + i * QK_S + seg) = *(const int4v*)(Kb + base + (size_t)i * 262144 + seg);
    }
    for (int idx = tid; idx < 1024; idx += 256) {       // V: 16B vector reads, LDS transpose
        int m = idx >> 3, seg = (idx & 7) * 8;
        short8v v = *(const short8v*)(Vb + base + (size_t)m * 262144 + seg);
        #pragma unroll
        for (int t = 0; t < 8; ++t)
            sVt[(seg + t) * VT_S + m] = (unsigned short)v[t];
    }
    __syncthreads();

    // Phase A: S = Q K^T  (wave (wm,wn) covers rows wm*64.., cols wn*64..)
    float4v zero4 = {0.f, 0.f, 0.f, 0.f};
    float4v S[4][4];
    #pragma unroll
    for (int a = 0; a < 4; ++a)
        #pragma unroll
        for (int b = 0; b < 4; ++b) S[a][b] = zero4;
    #pragma unroll
    for (int ks = 0; ks < 2; ++ks) {
        short8v qf[4], kf[4];
        #pragma unroll
        for (int t = 0; t < 4; ++t) {
            qf[t] = *(const short8v*)(sQ + (wm * 64 + t * 16 + l15) * QK_S + q4 * 8 + ks * 32);
            kf[t] = *(const short8v*)(sK + (wn * 64 + t * 16 + l15) * QK_S + q4 * 8 + ks * 32);
        }
        #pragma unroll
        for (int tm = 0; tm < 4; ++tm)
            #pragma unroll
            for (int tn = 0; tn < 4; ++tn)
                S[tm][tn] = __builtin_amdgcn_mfma_f32_16x16x32_bf16(qf[tm], kf[tn], S[tm][tn], 0, 0, 0);
    }

    // Row max (wave-local 64 cols -> cross-wave via LDS)
    float rmax[4][4];
    #pragma unroll
    for (int tm = 0; tm < 4; ++tm)
        #pragma unroll
        for (int g = 0; g < 4; ++g)
            rmax[tm][g] = fmaxf(fmaxf(S[tm][0][g], S[tm][1][g]), fmaxf(S[tm][2][g], S[tm][3][g]));
    #pragma unroll
    for (int off = 1; off <= 8; off <<= 1)
        #pragma unroll
        for (int tm = 0; tm < 4; ++tm)
            #pragma unroll
            for (int g = 0; g < 4; ++g)
                rmax[tm][g] = fmaxf(rmax[tm][g], __shfl_xor(rmax[tm][g], off, 64));
    if (l15 == 0) {
        #pragma unroll
        for (int tm = 0; tm < 4; ++tm)
            #pragma unroll
            for (int g = 0; g < 4; ++g)
                wred[0][wn][wm * 64 + tm * 16 + q4 * 4 + g] = rmax[tm][g];
    }
    __syncthreads();

    // exp + row sum
    float rsum[4][4];
    #pragma unroll
    for (int tm = 0; tm < 4; ++tm)
        #pragma unroll
        for (int g = 0; g < 4; ++g) {
            int r = wm * 64 + tm * 16 + q4 * 4 + g;
            float rm = fmaxf(wred[0][0][r], wred[0][1][r]);
            float t0 = 0.f;
            #pragma unroll
            for (int tn = 0; tn < 4; ++tn) {
                float e = __expf(S[tm][tn][g] - rm);
                S[tm][tn][g] = e;
                t0 += e;
            }
            rsum[tm][g] = t0;
        }
    #pragma unroll
    for (int off = 1; off <= 8; off <<= 1)
        #pragma unroll
        for (int tm = 0; tm < 4; ++tm)
            #pragma unroll
            for (int g = 0; g < 4; ++g)
                rsum[tm][g] += __shfl_xor(rsum[tm][g], off, 64);
    if (l15 == 0) {
        #pragma unroll
        for (int tm = 0; tm < 4; ++tm)
            #pragma unroll
            for (int g = 0; g < 4; ++g)
                wred[1][wn][wm * 64 + tm * 16 + q4 * 4 + g] = rsum[tm][g];
    }
    __syncthreads();

    // normalize w = e / rowsum
    #pragma unroll
    for (int tm = 0; tm < 4; ++tm)
        #pragma unroll
        for (int g = 0; g < 4; ++g) {
            int r = wm * 64 + tm * 16 + q4 * 4 + g;
            float inv = 1.0f / (wred[1][0][r] + wred[1][1][r]);
            #pragma unroll
            for (int tn = 0; tn < 4; ++tn) S[tm][tn][g] *= inv;
        }

    // avg_w column sums (sum over query rows)
    float cs[4];
    #pragma unroll
    for (int tn = 0; tn < 4; ++tn) {
        float t0 = 0.f;
        #pragma unroll
        for (int tm = 0; tm < 4; ++tm)
            #pragma unroll
            for (int g = 0; g < 4; ++g) t0 += S[tm][tn][g];
        cs[tn] = t0;
    }
    #pragma unroll
    for (int off = 16; off <= 32; off <<= 1)
        #pragma unroll
        for (int tn = 0; tn < 4; ++tn) cs[tn] += __shfl_xor(cs[tn], off, 64);
    if (lane < 16) {
        #pragma unroll
        for (int tn = 0; tn < 4; ++tn)
            atomicAdd(&colsum[wn * 64 + tn * 16 + lane], cs[tn]);
    }
    __syncthreads();   // sQ/sK reads & colsum atomics complete block-wide

    // write P (bf16) into region0 (aliases sQ/sK — safe now)
    #pragma unroll
    for (int tm = 0; tm < 4; ++tm)
        #pragma unroll
        for (int tn = 0; tn < 4; ++tn)
            #pragma unroll
            for (int g = 0; g < 4; ++g)
                sP[(wm * 64 + tm * 16 + q4 * 4 + g) * P_S + wn * 64 + tn * 16 + l15] = f2bf(S[tm][tn][g]);
    __syncthreads();

    if (tid < 128) avgw[(size_t)j * 128 + tid] = colsum[tid] * (1.0f / 16.0f);

    // Phase C: O = P V (via transposed V). Wave covers rows wm*64.., cols wn*32..
    float4v O[4][2];
    #pragma unroll
    for (int a = 0; a < 4; ++a) { O[a][0] = zero4; O[a][1] = zero4; }
    #pragma unroll
    for (int ks = 0; ks < 4; ++ks) {
        short8v pf[4], vf[2];
        #pragma unroll
        for (int t = 0; t < 4; ++t)
            pf[t] = *(const short8v*)(sP + (wm * 64 + t * 16 + l15) * P_S + q4 * 8 + ks * 32);
        #pragma unroll
        for (int t = 0; t < 2; ++t)
            vf[t] = *(const short8v*)(sVt + (wn * 32 + t * 16 + l15) * VT_S + q4 * 8 + ks * 32);
        #pragma unroll
        for (int tm = 0; tm < 4; ++tm)
            #pragma unroll
            for (int tn = 0; tn < 2; ++tn)
                O[tm][tn] = __builtin_amdgcn_mfma_f32_16x16x32_bf16(pf[tm], vf[tn], O[tm][tn], 0, 0, 0);
    }
    #pragma unroll
    for (int tm = 0; tm < 4; ++tm)
        #pragma unroll
        for (int tn = 0; tn < 2; ++tn)
            #pragma unroll
            for (int g = 0; g < 4; ++g) {
                int i = wm * 64 + tm * 16 + q4 * 4 + g;
                int d = wn * 32 + tn * 16 + l15;
                attnb[base + (size_t)i * 262144 + d] = f2bf(O[tm][tn][g]);
            }
}

// ---------------------------------------------------------------- K4: residual + LN2
__global__ __launch_bounds__(256) void k4_ln2(const float* __restrict__ x,
                                              const float* __restrict__ w1,
                                              const float* __restrict__ b1,
                                              const unsigned short* __restrict__ attnb,
                                              const float* __restrict__ w2,
                                              const float* __restrict__ b2,
                                              float* __restrict__ out) {
    __shared__ float red[8];
    int row = blockIdx.x;
    int tid = threadIdx.x;
    float4v xv = ((const float4v*)(x + (size_t)row * 1024))[tid];
    float s  = xv[0] + xv[1] + xv[2] + xv[3];
    float s2 = xv[0]*xv[0] + xv[1]*xv[1] + xv[2]*xv[2] + xv[3]*xv[3];
    block_reduce_2(s, s2, red);
    float mean = s * (1.0f / 1024.0f);
    float var  = s2 * (1.0f / 1024.0f) - mean * mean;
    float rs   = rsqrtf(var + LN_EPS);
    float4v wv = ((const float4v*)w1)[tid];
    float4v bv = ((const float4v*)b1)[tid];
    short4v av = ((const short4v*)(attnb + (size_t)row * 1024))[tid];
    float4v r;
    #pragma unroll
    for (int c = 0; c < 4; ++c)
        r[c] = (xv[c] - mean) * rs * wv[c] + bv[c] + bf2f((unsigned short)av[c]);
    s  = r[0] + r[1] + r[2] + r[3];
    s2 = r[0]*r[0] + r[1]*r[1] + r[2]*r[2] + r[3]*r[3];
    block_reduce_2(s, s2, red);
    float mean2 = s * (1.0f / 1024.0f);
    float var2  = s2 * (1.0f / 1024.0f) - mean2 * mean2;
    float rs2   = rsqrtf(var2 + LN_EPS);
    float4v w2v = ((const float4v*)w2)[tid];
    float4v b2v = ((const float4v*)b2)[tid];
    float4v o;
    #pragma unroll
    for (int c = 0; c < 4; ++c)
        o[c] = (r[c] - mean2) * rs2 * w2v[c] + b2v[c];
    ((float4v*)(out + (size_t)row * 1024))[tid] = o;
}

// ---------------------------------------------------------------- launch
extern "C" void kernel_launch(void* const* d_in, const int* in_sizes, int n_in,
                              void* d_out, int out_size, void* d_ws, size_t ws_size,
                              hipStream_t stream) {
    const float* x    = (const float*)d_in[0];
    const float* ln1w = (const float*)d_in[1];
    const float* ln1b = (const float*)d_in[2];
    const float* inw  = (const float*)d_in[3];
    const float* inb  = (const float*)d_in[4];
    const float* ln2w = (const float*)d_in[5];
    const float* ln2b = (const float*)d_in[6];
    float* out  = (float*)d_out;
    float* avgw = out + 33554432;           // 256*128*1024

    char* ws = (char*)d_ws;                 // needs ~275 MB
    unsigned short* xnb = (unsigned short*)(ws);                 // also attnb (reused)
    unsigned short* Qb  = (unsigned short*)(ws + 67108864);
    unsigned short* Kb  = (unsigned short*)(ws + 134217728);
    unsigned short* Vb  = (unsigned short*)(ws + 201326592);
    unsigned short* Wb  = (unsigned short*)(ws + 268435456);

    k0_w_to_bf16<<<1536, 256, 0, stream>>>(inw, Wb);
    k1_ln1<<<32768, 256, 0, stream>>>(x, ln1w, ln1b, xnb);
    k2_qkv_gemm<<<6144, 256, 0, stream>>>(xnb, Wb, inb, Qb, Kb, Vb);
    k3_attn<<<4096, 256, 0, stream>>>(Qb, Kb, Vb, xnb /*attnb*/, avgw);
    k4_ln2<<<32768, 256, 0, stream>>>(x, ln1w, ln1b, xnb /*attnb*/, ln2w, ln2b, out);
}